// Round 5
// baseline (72.913 us; speedup 1.0000x reference)
//
#include <hip/hip_runtime.h>

typedef float  v4f    __attribute__((ext_vector_type(4)));
typedef float  f32x4  __attribute__((ext_vector_type(4)));
typedef short  bf16x8 __attribute__((ext_vector_type(8)));

namespace {
constexpr int XSTR  = 268;   // xall row stride (f32): 268 mod 32 = 12 -> spreads banks, 16B-aligned
constexpr int ASTR  = 264;   // att row stride (f32)
constexpr int MWSTR = 132;   // mw row stride (f32)
constexpr int XDSTR = 68;    // xd row stride (f32)
constexpr int MSTR  = 72;    // mbf/abf row stride (bf16)

__device__ __forceinline__ float fsilu(float v){ return v/(1.f+__expf(-v)); }
__device__ __forceinline__ float fsigm(float v){ return 1.f/(1.f+__expf(-v)); }
__device__ __forceinline__ short f2bf(float f){          // fp32 -> bf16 RNE
  unsigned u = __builtin_bit_cast(unsigned, f);
  return (short)((u + 0x7FFFu + ((u>>16)&1u)) >> 16);
}
// async global->LDS, 16B per lane; LDS dst = uniform base + lane*16
__device__ __forceinline__ void gload_lds16(const float* g, float* lds) {
  __builtin_amdgcn_global_load_lds(
      (const __attribute__((address_space(1))) unsigned int*)g,
      (__attribute__((address_space(3))) unsigned int*)lds, 16, 0, 0);
}
__device__ __forceinline__ bf16x8 pack_bf8(const float* src) {
  v4f lo = *(const v4f*)src;
  v4f hi = *(const v4f*)(src + 4);
  bf16x8 a;
  a[0]=f2bf(lo.x); a[1]=f2bf(lo.y); a[2]=f2bf(lo.z); a[3]=f2bf(lo.w);
  a[4]=f2bf(hi.x); a[5]=f2bf(hi.y); a[6]=f2bf(hi.z); a[7]=f2bf(hi.w);
  return a;
}
}

__global__ __launch_bounds__(256, 4)
void fused_gnn_v4(const float* __restrict__ x,
                  const float* __restrict__ Wd, const float* __restrict__ bd,
                  const float* __restrict__ bn1s, const float* __restrict__ bn1b,
                  const float* __restrict__ bn1m, const float* __restrict__ bn1v,
                  const float* __restrict__ Wc,
                  const float* __restrict__ bn2s, const float* __restrict__ bn2b,
                  const float* __restrict__ bn2m, const float* __restrict__ bn2v,
                  const float* __restrict__ Wa, const float* __restrict__ ba,
                  float* __restrict__ out, int nbat)
{
  __shared__ float xall[18*XSTR];          // rows 0..16 = x (f32); row 17 = zeros (clamp target)
  __shared__ float uni [5*ASTR];           // union: xd[17][68] | mw[5][132] | att[5][264]
  __shared__ short mbf [16*MSTR];          // means bf16, rows 5..15 zeroed
  __shared__ short abf [16*MSTR];          // agg   bf16, rows 5..15 zeroed
  __shared__ float a1c[64], b1c[64], a2c[64], b2c[64];

  float* xd  = uni;
  float* mw  = uni;
  float* att = uni;

  const int tid  = threadIdx.x;
  const int l    = tid & 63;
  const int wv   = tid >> 6;          // wave 0..3
  const int arow = l & 15;
  const int ak8  = (l >> 4) * 8;      // k-offset of this lane's 8-elem A/B slice

  // ---- one-time: fold BN affines (b_down into bn1 bias) ----
  if (tid < 64) {
    float av = bn1s[tid] * rsqrtf(bn1v[tid] + 1e-5f);
    a1c[tid] = av; b1c[tid] = (bd[tid] - bn1m[tid])*av + bn1b[tid];
    float av2 = bn2s[tid] * rsqrtf(bn2v[tid] + 1e-5f);
    a2c[tid] = av2; b2c[tid] = bn2b[tid] - bn2m[tid]*av2;
  }
  // ---- one-time: zero pad rows ----
  for (int u = tid; u < XSTR; u += 256) xall[17*XSTR + u] = 0.f;
  for (int u = tid; u < 11*MSTR; u += 256) { mbf[5*MSTR + u] = 0; abf[5*MSTR + u] = 0; }

  // ---- one-time: weight B-fragments into registers ----
  // Phase A: B[k][n] = Wd[k][n]; this wave's n-tile = wv (N=64 -> 4 tiles)
  const int colA = wv*16 + arow;
  bf16x8 Bd[8];
  #pragma unroll
  for (int ks = 0; ks < 8; ++ks) {
    bf16x8 f;
    #pragma unroll
    for (int j = 0; j < 8; ++j) f[j] = f2bf(Wd[(ks*32 + ak8 + j)*64 + colA]);
    Bd[ks] = f;
  }
  // Phase B2: B[i][(w,o)] = Wc[o][w*64+i]; wave handles 2 n-tiles of N=128
  bf16x8 Bc[2][2];
  #pragma unroll
  for (int t = 0; t < 2; ++t) {
    const int colC = (wv*2 + t)*16 + arow;
    const int cw = colC >> 6, co = colC & 63;
    #pragma unroll
    for (int ks = 0; ks < 2; ++ks) {
      bf16x8 f;
      #pragma unroll
      for (int j = 0; j < 8; ++j) f[j] = f2bf(Wc[co*128 + cw*64 + ks*32 + ak8 + j]);
      Bc[t][ks] = f;
    }
  }
  // Phase E: B[i][c] = Wa[i][c]; wave handles 4 n-tiles of N=256
  bf16x8 Ba[4][2];
  float  bav[4];
  #pragma unroll
  for (int t = 0; t < 4; ++t) {
    const int colE = wv*64 + t*16 + arow;
    bav[t] = ba[colE];
    #pragma unroll
    for (int ks = 0; ks < 2; ++ks) {
      bf16x8 f;
      #pragma unroll
      for (int j = 0; j < 8; ++j) f[j] = f2bf(Wa[(ks*32 + ak8 + j)*256 + colE]);
      Ba[t][ks] = f;
    }
  }

  for (int it = 0; it < nbat; ++it) {
    const int batch = blockIdx.x * nbat + it;
    const float* xb = x + (size_t)batch * 4352;

    // ---- stage x rows via async global->LDS (16B/lane; one row per wave-instr) ----
    for (int r = wv; r < 17; r += 4)
      gload_lds16(xb + r*256 + l*4, &xall[r*XSTR]);
    __syncthreads();   // drains vmcnt

    // ---- Phase A (MFMA): xd = silu(bn1(x @ Wd)), rows 0..16, N=64, K=256 ----
    {
      f32x4 acc0 = {0.f,0.f,0.f,0.f};   // rows 0..15
      f32x4 acc1 = {0.f,0.f,0.f,0.f};   // row 16 (clamped tile)
      const int rowT = (arow == 0) ? 16 : 17;   // rows 17.. read the zero row
      #pragma unroll
      for (int ks = 0; ks < 8; ++ks) {
        bf16x8 a0 = pack_bf8(&xall[arow*XSTR + ks*32 + ak8]);
        acc0 = __builtin_amdgcn_mfma_f32_16x16x32_bf16(a0, Bd[ks], acc0, 0, 0, 0);
        bf16x8 a1 = pack_bf8(&xall[rowT*XSTR + ks*32 + ak8]);
        acc1 = __builtin_amdgcn_mfma_f32_16x16x32_bf16(a1, Bd[ks], acc1, 0, 0, 0);
      }
      const float av = a1c[colA], bv = b1c[colA];
      #pragma unroll
      for (int j = 0; j < 4; ++j) {
        const int r = (l>>4)*4 + j;
        xd[r*XDSTR + colA] = fsilu(acc0[j]*av + bv);
      }
      if ((l >> 4) == 0)                 // tile row 0 == batch row 16
        xd[16*XDSTR + colA] = fsilu(acc1[0]*av + bv);
    }
    __syncthreads();

    // ---- Phase B1: group means -> bf16 ----
    for (int u = tid; u < 320; u += 256) {
      const int g = u >> 6, i = u & 63;
      float m;
      if (g == 0) {
        m = (xd[0*XDSTR+i]+xd[1*XDSTR+i]+xd[2*XDSTR+i]
            +xd[3*XDSTR+i]+xd[4*XDSTR+i])*0.2f;
      } else {
        const int kb = (g==1)?5:(g==2)?6:(g==3)?11:12;
        m = (xd[kb*XDSTR+i] + xd[(kb+2)*XDSTR+i] + xd[(kb+4)*XDSTR+i])*(1.f/3.f);
      }
      mbf[g*MSTR + i] = f2bf(m);
    }
    __syncthreads();

    // ---- Phase B2 (MFMA): mw[g][(w,o)] = means @ Wc-halves, M=5, N=128, K=64 ----
    {
      f32x4 accB0 = {0.f,0.f,0.f,0.f}, accB1 = {0.f,0.f,0.f,0.f};
      #pragma unroll
      for (int ks = 0; ks < 2; ++ks) {
        bf16x8 a = *(const bf16x8*)&mbf[arow*MSTR + ks*32 + ak8];
        accB0 = __builtin_amdgcn_mfma_f32_16x16x32_bf16(a, Bc[0][ks], accB0, 0, 0, 0);
        accB1 = __builtin_amdgcn_mfma_f32_16x16x32_bf16(a, Bc[1][ks], accB1, 0, 0, 0);
      }
      #pragma unroll
      for (int j = 0; j < 4; ++j) {
        const int g = (l>>4)*4 + j;
        if (g < 5) {
          mw[g*MWSTR + (wv*2+0)*16 + arow] = accB0[j];
          mw[g*MWSTR + (wv*2+1)*16 + arow] = accB1[j];
        }
      }
    }
    __syncthreads();

    // ---- Phase B3: agg[g][o] = sum_{cc!=g} silu(bn2(mw1[g]-mw2[g]+mw2[cc])) ----
    for (int u = tid; u < 320; u += 256) {
      const int g = u >> 6, o = u & 63;
      const float bse = mw[g*MWSTR + o] - mw[g*MWSTR + 64 + o];
      const float av = a2c[o], bv = b2c[o];
      float s = 0.f;
      #pragma unroll
      for (int cc = 0; cc < 5; ++cc) {
        if (cc != g) s += fsilu((bse + mw[cc*MWSTR + 64 + o])*av + bv);
      }
      abf[g*MSTR + o] = f2bf(s);
    }
    __syncthreads();

    // ---- Phase E (MFMA): att = sigmoid(agg @ Wa + ba), M=5, N=256, K=64 ----
    {
      bf16x8 ae[2];
      #pragma unroll
      for (int ks = 0; ks < 2; ++ks)
        ae[ks] = *(const bf16x8*)&abf[arow*MSTR + ks*32 + ak8];
      f32x4 accE[4] = {{0.f,0.f,0.f,0.f},{0.f,0.f,0.f,0.f},
                       {0.f,0.f,0.f,0.f},{0.f,0.f,0.f,0.f}};
      #pragma unroll
      for (int t = 0; t < 4; ++t) {
        #pragma unroll
        for (int ks = 0; ks < 2; ++ks)
          accE[t] = __builtin_amdgcn_mfma_f32_16x16x32_bf16(ae[ks], Ba[t][ks], accE[t], 0, 0, 0);
      }
      #pragma unroll
      for (int t = 0; t < 4; ++t) {
        #pragma unroll
        for (int j = 0; j < 4; ++j) {
          const int g = (l>>4)*4 + j;
          if (g < 5) att[g*ASTR + wv*64 + t*16 + arow] = fsigm(accE[t][j] + bav[t]);
        }
      }
    }
    __syncthreads();

    // ---- Phase F: out[k][c] = x[k][c] * att[GOF[k]][c] ----
    {
      const int c = tid;
      float a5[5];
      #pragma unroll
      for (int g = 0; g < 5; ++g) a5[g] = att[g*ASTR + c];
      float* ob = out + (size_t)batch * 4352 + c;
      constexpr int GOF[17] = {0,0,0,0,0,1,2,1,2,1,2,3,4,3,4,3,4};
      #pragma unroll
      for (int k = 0; k < 17; ++k)
        ob[k*256] = xall[k*XSTR + c] * a5[GOF[k]];
    }
    __syncthreads();   // protect xall/uni before next iteration's staging
  }
}

extern "C" void kernel_launch(void* const* d_in, const int* in_sizes, int n_in,
                              void* d_out, int out_size, void* d_ws, size_t ws_size,
                              hipStream_t stream) {
    (void)n_in; (void)out_size; (void)d_ws; (void)ws_size;
    const float* x   = (const float*)d_in[0];
    const float* Wd  = (const float*)d_in[1];
    const float* bd  = (const float*)d_in[2];
    const float* s1  = (const float*)d_in[3];
    const float* b1  = (const float*)d_in[4];
    const float* m1  = (const float*)d_in[5];
    const float* v1  = (const float*)d_in[6];
    const float* Wc  = (const float*)d_in[7];
    const float* s2  = (const float*)d_in[8];
    const float* b2  = (const float*)d_in[9];
    const float* m2  = (const float*)d_in[10];
    const float* v2  = (const float*)d_in[11];
    const float* Wa  = (const float*)d_in[12];
    const float* ba  = (const float*)d_in[13];

    const int Btot = in_sizes[0] / (17 * 256);   // 4096
    const int nbat = 4;                           // batches per block
    const int GRID = Btot / nbat;                 // 1024 blocks -> 4 per CU

    fused_gnn_v4<<<GRID, 256, 0, stream>>>(
        x, Wd, bd, s1, b1, m1, v1, Wc, s2, b2, m2, v2, Wa, ba,
        (float*)d_out, nbat);
}